// Round 6
// baseline (79.145 us; speedup 1.0000x reference)
//
#include <hip/hip_runtime.h>

#define BB 16
#define HH 512
#define WW 512
#define TH 32
#define TW 64
#define HALO 8
#define MAXROWS (TH + 2 * HALO + 1)     // 49
#define STRIDEW 252                      // words per staged row (84 px * 3), 84 = max padded width

typedef float vf4 __attribute__((ext_vector_type(4)));

__global__ __launch_bounds__(256) void warp2_kernel(
    const float* __restrict__ frame0,
    const float* __restrict__ frame1,
    const float* __restrict__ f01,
    const float* __restrict__ f10,
    float* __restrict__ out)
{
    __shared__ float lds[MAXROWS * STRIDEW];   // 49*252*4 = 49,392 B

    // ---- tile decode with bijective XCD-chunked swizzle (4096 = 8 * 512) ----
    const int bid = blockIdx.x;
    const int gt  = (bid & 7) * 512 + (bid >> 3);
    const int which = gt >= 2048;            // 0: out0=warp(frame0,f10), 1: out1=warp(frame1,f01)
    const int t2 = gt & 2047;
    const int b  = t2 >> 7;                  // 128 tiles per image
    const int tt = t2 & 127;
    const int rowtile = tt >> 3;             // 16 row tiles
    const int coltile = tt & 7;              // 8 col tiles (coltile fastest -> L2 row reuse)
    const int ty = rowtile * TH;
    const int tx = coltile * TW;

    const float* __restrict__ img  = which ? frame1 : frame0;
    const float* __restrict__ flow = which ? f01    : f10;

    // ---- staged region [r0..r1] x [c0..c1], width padded to multiple of 4 px ----
    const int r0 = max(0, ty - HALO);
    const int r1 = min(HH - 1, ty + TH + HALO);
    int c0 = max(0, tx - HALO);
    int c1 = min(WW - 1, tx + TW + HALO);
    {
        const int rem = (c1 - c0 + 1) & 3;
        if (rem) {
            const int pad = 4 - rem;
            if (c0 >= pad) c0 -= pad; else c1 += pad;   // c1+pad stays <= 511 when c0 is clamped at 0
        }
    }
    const int nrows = r1 - r0 + 1;                 // <= 49
    const int chunks_row = ((c1 - c0 + 1) * 3) >> 2; // 16B chunks per row, <= 63

    const int tid  = threadIdx.x;
    const int lane = tid & 63;
    const int wid  = tid >> 6;

    // ---- stage: one wave per row, one 16B chunk per lane (coalesced) ----
    for (int row = wid; row < nrows; row += 4) {
        if (lane < chunks_row) {
            const size_t gword = ((size_t)((b * HH + r0 + row) * WW + c0)) * 3 + (lane << 2);
            const vf4 v = *reinterpret_cast<const vf4*>(img + gword);
            *reinterpret_cast<vf4*>(&lds[row * STRIDEW + (lane << 2)]) = v;
        }
    }
    __syncthreads();

    // ---- gather: 4 pair-iterations, 2 px per iteration per thread ----
    for (int p = 0; p < 4; ++p) {
        const int idx = (p << 8) + tid;            // pair index in tile, 0..1023
        const int row = idx >> 5;                  // 0..31
        const int pc  = idx & 31;                  // pair col 0..31
        const int y = ty + row;
        const int x = tx + (pc << 1);

        const size_t pairI = (((size_t)(b * HH + y)) << 8) + (tx >> 1) + pc;
        const vf4 fl = __builtin_nontemporal_load(
            reinterpret_cast<const vf4*>(flow + 4 * pairI));

        float res[6];
        #pragma unroll
        for (int s = 0; s < 2; ++s) {
            const float dy = s ? fl.z : fl.x;
            const float dx = s ? fl.w : fl.y;
            const int xs = x + s;

            const float qy = (float)y - dy;
            const float qx = (float)xs - dx;
            const float y0f = fminf(fmaxf(floorf(qy), 0.0f), (float)(HH - 2));
            const float x0f = fminf(fmaxf(floorf(qx), 0.0f), (float)(WW - 2));
            const float ay = fminf(fmaxf(qy - y0f, 0.0f), 1.0f);
            const float ax = fminf(fmaxf(qx - x0f, 0.0f), 1.0f);
            const int y0 = (int)y0f;
            const int x0 = (int)x0f;

            float tl0, tl1, tl2, tr0, tr1, tr2, bl0, bl1, bl2, br0, br1, br2;
            if (y0 >= r0 && y0 < r1 && x0 >= c0 && x0 < c1) {
                // LDS path (covers |flow| < HALO; x0 < c1 guarantees tr/br in range)
                const int bw = (y0 - r0) * STRIDEW + (x0 - c0) * 3;
                tl0 = lds[bw];              tl1 = lds[bw + 1];            tl2 = lds[bw + 2];
                tr0 = lds[bw + 3];          tr1 = lds[bw + 4];            tr2 = lds[bw + 5];
                bl0 = lds[bw + STRIDEW];    bl1 = lds[bw + STRIDEW + 1];  bl2 = lds[bw + STRIDEW + 2];
                br0 = lds[bw + STRIDEW + 3];br1 = lds[bw + STRIDEW + 4];  br2 = lds[bw + STRIDEW + 5];
            } else {
                // rare outlier fallback: exact same math from global
                const float* rowt = img + ((size_t)((b * HH + y0) * WW + x0)) * 3;
                const float* rowb = rowt + WW * 3;
                const float3 tl = *reinterpret_cast<const float3*>(rowt);
                const float3 tr = *reinterpret_cast<const float3*>(rowt + 3);
                const float3 bl = *reinterpret_cast<const float3*>(rowb);
                const float3 br = *reinterpret_cast<const float3*>(rowb + 3);
                tl0 = tl.x; tl1 = tl.y; tl2 = tl.z;
                tr0 = tr.x; tr1 = tr.y; tr2 = tr.z;
                bl0 = bl.x; bl1 = bl.y; bl2 = bl.z;
                br0 = br.x; br1 = br.y; br2 = br.z;
            }

            const float t0 = fmaf(ax, tr0 - tl0, tl0);
            const float t1 = fmaf(ax, tr1 - tl1, tl1);
            const float t2v = fmaf(ax, tr2 - tl2, tl2);
            const float q0 = fmaf(ax, br0 - bl0, bl0);
            const float q1 = fmaf(ax, br1 - bl1, bl1);
            const float q2 = fmaf(ax, br2 - bl2, bl2);
            res[3 * s + 0] = fmaf(ay, q0 - t0, t0);
            res[3 * s + 1] = fmaf(ay, q1 - t1, t1);
            res[3 * s + 2] = fmaf(ay, q2 - t2v, t2v);
        }

        const size_t pix = ((size_t)which) * (BB * HH * WW) + (size_t)(b * HH + y) * WW + x;
        float* o = out + 3 * pix;
        *reinterpret_cast<float3*>(o)     = make_float3(res[0], res[1], res[2]);
        *reinterpret_cast<float3*>(o + 3) = make_float3(res[3], res[4], res[5]);
    }
}

extern "C" void kernel_launch(void* const* d_in, const int* in_sizes, int n_in,
                              void* d_out, int out_size, void* d_ws, size_t ws_size,
                              hipStream_t stream) {
    const float* frame0 = (const float*)d_in[0];
    const float* frame1 = (const float*)d_in[1];
    const float* f01    = (const float*)d_in[2];
    const float* f10    = (const float*)d_in[3];
    float* out = (float*)d_out;

    // 2 outputs * 16 batches * 16 rowtiles * 8 coltiles = 4096 blocks
    warp2_kernel<<<4096, 256, 0, stream>>>(frame0, frame1, f01, f10, out);
}

// Round 7
// 74.241 us; speedup vs baseline: 1.0661x; 1.0661x over previous
//
#include <hip/hip_runtime.h>

#define BB 16
#define HH 512
#define WW 512
#define TH 16
#define TW 32
#define HALO 8
#define SR 33                    // staged rows = TH + 2*HALO + 1
#define SC 48                    // staged cols (px), constant for every tile
#define CHUNKS 36                // 16B chunks per staged row = SC*3/4
#define STRIDEW 144              // floats per staged row = SC*3
#define NCHUNK (SR * CHUNKS)     // 1188

typedef float vf4 __attribute__((ext_vector_type(4)));

__global__ __launch_bounds__(256) void warp2_kernel(
    const float* __restrict__ frame0,
    const float* __restrict__ frame1,
    const float* __restrict__ f01,
    const float* __restrict__ f10,
    float* __restrict__ out)
{
    __shared__ float lds[SR * STRIDEW];      // 19,008 B -> 8 blocks/CU

    // ---- tile decode, bijective XCD-chunked swizzle (16384 = 8 * 2048) ----
    const int bid = blockIdx.x;
    const int gt  = (bid & 7) * 2048 + (bid >> 3);
    const int which   = gt >> 13;            // 8192 tiles per output
    const int b       = (gt >> 9) & 15;      // batch
    const int tt      = gt & 511;
    const int rowtile = tt >> 4;             // 0..31
    const int coltile = tt & 15;             // 0..15 (fastest -> L2 row reuse)
    const int ty = rowtile * TH;
    const int tx = coltile * TW;

    const float* __restrict__ img  = which ? frame1 : frame0;
    const float* __restrict__ flow = which ? f01    : f10;

    // constant-size staged window, clamped placement (always fully in-bounds)
    const int r0 = min(max(ty - HALO, 0), HH - SR);   // 33 rows staged
    const int c0 = min(max(tx - HALO, 0), WW - SC);   // 48 px staged, mult of 4

    const int tid = threadIdx.x;

    // ---- stage: flattened, all 256 threads, 16B chunks (coalesced, 16B-aligned) ----
    for (int c = tid; c < NCHUNK; c += 256) {
        const int row = c / CHUNKS;                  // const divisor -> magic mul
        const int col = c - row * CHUNKS;
        const size_t gw = ((size_t)((b * HH + r0 + row) * WW + c0)) * 3 + (col << 2);
        *reinterpret_cast<vf4*>(&lds[row * STRIDEW + (col << 2)]) =
            *reinterpret_cast<const vf4*>(img + gw);
    }
    __syncthreads();

    // ---- gather: one pair (2 px) per thread ----
    const int row = tid >> 4;                // 0..15
    const int pc  = tid & 15;                // pair col 0..15
    const int y = ty + row;
    const int x = tx + (pc << 1);

    const size_t pairI = (((size_t)(b * HH + y)) << 8) + (tx >> 1) + pc;
    const vf4 fl = __builtin_nontemporal_load(
        reinterpret_cast<const vf4*>(flow + 4 * pairI));

    float res[6];
    #pragma unroll
    for (int s = 0; s < 2; ++s) {
        const float dy = s ? fl.z : fl.x;
        const float dx = s ? fl.w : fl.y;
        const int xs = x + s;

        const float qy = (float)y - dy;
        const float qx = (float)xs - dx;
        const float y0f = fminf(fmaxf(floorf(qy), 0.0f), (float)(HH - 2));
        const float x0f = fminf(fmaxf(floorf(qx), 0.0f), (float)(WW - 2));
        const float ay = fminf(fmaxf(qy - y0f, 0.0f), 1.0f);
        const float ax = fminf(fmaxf(qx - x0f, 0.0f), 1.0f);
        const int y0 = (int)y0f;
        const int x0 = (int)x0f;

        float tl0, tl1, tl2, tr0, tr1, tr2, bl0, bl1, bl2, br0, br1, br2;
        // need y0+1 <= r0+SR-1 and x0+1 <= c0+SC-1
        if (y0 >= r0 && y0 < r0 + SR - 1 && x0 >= c0 && x0 < c0 + SC - 1) {
            const int bw = (y0 - r0) * STRIDEW + (x0 - c0) * 3;
            tl0 = lds[bw];               tl1 = lds[bw + 1];             tl2 = lds[bw + 2];
            tr0 = lds[bw + 3];           tr1 = lds[bw + 4];             tr2 = lds[bw + 5];
            bl0 = lds[bw + STRIDEW];     bl1 = lds[bw + STRIDEW + 1];   bl2 = lds[bw + STRIDEW + 2];
            br0 = lds[bw + STRIDEW + 3]; br1 = lds[bw + STRIDEW + 4];   br2 = lds[bw + STRIDEW + 5];
        } else {
            // rare |flow| > HALO outlier: exact fallback from global
            const float* rowt = img + ((size_t)((b * HH + y0) * WW + x0)) * 3;
            const float* rowb = rowt + WW * 3;
            const float3 tl = *reinterpret_cast<const float3*>(rowt);
            const float3 tr = *reinterpret_cast<const float3*>(rowt + 3);
            const float3 bl = *reinterpret_cast<const float3*>(rowb);
            const float3 br = *reinterpret_cast<const float3*>(rowb + 3);
            tl0 = tl.x; tl1 = tl.y; tl2 = tl.z;
            tr0 = tr.x; tr1 = tr.y; tr2 = tr.z;
            bl0 = bl.x; bl1 = bl.y; bl2 = bl.z;
            br0 = br.x; br1 = br.y; br2 = br.z;
        }

        const float t0 = fmaf(ax, tr0 - tl0, tl0);
        const float t1 = fmaf(ax, tr1 - tl1, tl1);
        const float t2 = fmaf(ax, tr2 - tl2, tl2);
        const float q0 = fmaf(ax, br0 - bl0, bl0);
        const float q1 = fmaf(ax, br1 - bl1, bl1);
        const float q2 = fmaf(ax, br2 - bl2, bl2);
        res[3 * s + 0] = fmaf(ay, q0 - t0, t0);
        res[3 * s + 1] = fmaf(ay, q1 - t1, t1);
        res[3 * s + 2] = fmaf(ay, q2 - t2, t2);
    }

    const size_t pix = ((size_t)which) * (BB * HH * WW) + (size_t)(b * HH + y) * WW + x;
    float* o = out + 3 * pix;
    *reinterpret_cast<float3*>(o)     = make_float3(res[0], res[1], res[2]);
    *reinterpret_cast<float3*>(o + 3) = make_float3(res[3], res[4], res[5]);
}

extern "C" void kernel_launch(void* const* d_in, const int* in_sizes, int n_in,
                              void* d_out, int out_size, void* d_ws, size_t ws_size,
                              hipStream_t stream) {
    const float* frame0 = (const float*)d_in[0];
    const float* frame1 = (const float*)d_in[1];
    const float* f01    = (const float*)d_in[2];
    const float* f10    = (const float*)d_in[3];
    float* out = (float*)d_out;

    // 2 outputs * 16 batches * 32 rowtiles * 16 coltiles = 16384 blocks
    warp2_kernel<<<16384, 256, 0, stream>>>(frame0, frame1, f01, f10, out);
}

// Round 8
// 65.836 us; speedup vs baseline: 1.2021x; 1.1277x over previous
//
#include <hip/hip_runtime.h>

#define BB 16
#define HH 512
#define WW 512
#define TH 16
#define TW 64
#define HALO 8
#define SR 33                 // staged rows = TH + 2*HALO + 1
#define SC 80                 // staged cols (px) = TW + 2*HALO
#define PSTRIDE (SR * SC)     // 2640 floats per channel plane
#define ROWQ (SC / 4)         // 20 quad-px units per staged row
#define NUNIT (SR * ROWQ)     // 660 staging units
#define NPIX (BB * HH * WW)

typedef float vf4 __attribute__((ext_vector_type(4)));

__global__ __launch_bounds__(256, 5) void warp2_kernel(
    const float* __restrict__ frame0,
    const float* __restrict__ frame1,
    const float* __restrict__ f01,
    const float* __restrict__ f10,
    float* __restrict__ out)
{
    __shared__ float lds[3 * PSTRIDE];   // 31,680 B -> 5 blocks/CU

    // ---- tile decode, bijective XCD-chunked swizzle (8192 = 8 * 1024) ----
    const int bid = blockIdx.x;
    const int gt  = (bid & 7) * 1024 + (bid >> 3);
    const int which = gt >> 12;          // 4096 tiles per output
    const int b     = (gt >> 8) & 15;
    const int tt    = gt & 255;
    const int ty    = (tt >> 3) * TH;    // 32 rowtiles
    const int tx    = (tt & 7) * TW;     // 8 coltiles, fastest -> L2 reuse

    const float* __restrict__ img  = which ? frame1 : frame0;
    const float* __restrict__ flow = which ? f01    : f10;

    const int r0 = min(max(ty - HALO, 0), HH - SR);
    const int c0 = min(max(tx - HALO, 0), WW - SC);

    const int tid = threadIdx.x;

    // ---- flow prefetch (issued BEFORE staging so latency hides under it) ----
    const int r  = tid >> 4;             // 0..15 row in tile
    const int q  = tid & 15;             // 0..15 quad in row
    const int y  = ty + r;
    const int xq = tx + (q << 2);        // first of 4 consecutive px
    const size_t pixbase = (size_t)(b * HH + y) * WW + xq;
    const vf4 fl0 = __builtin_nontemporal_load(reinterpret_cast<const vf4*>(flow + 2 * pixbase));
    const vf4 fl1 = __builtin_nontemporal_load(reinterpret_cast<const vf4*>(flow + 2 * pixbase + 4));

    // ---- stage into SoA planes: 660 quad-px units, 3 iters (last guarded) ----
    #pragma unroll
    for (int it = 0; it < 3; ++it) {
        const int s = tid + (it << 8);
        if (it < 2 || s < NUNIT) {
            const int row = s / ROWQ;                    // const-div -> magic mul
            const int u   = s - row * ROWQ;
            const float* g = img + ((size_t)((b * HH + r0 + row) * WW + c0 + (u << 2))) * 3;
            const vf4 a0 = *reinterpret_cast<const vf4*>(g);
            const vf4 a1 = *reinterpret_cast<const vf4*>(g + 4);
            const vf4 a2 = *reinterpret_cast<const vf4*>(g + 8);
            const int base = row * SC + (u << 2);
            const vf4 R = {a0.x, a0.w, a1.z, a2.y};
            const vf4 G = {a0.y, a1.x, a1.w, a2.z};
            const vf4 B = {a0.z, a1.y, a2.x, a2.w};
            *reinterpret_cast<vf4*>(&lds[base])               = R;
            *reinterpret_cast<vf4*>(&lds[PSTRIDE + base])     = G;
            *reinterpret_cast<vf4*>(&lds[2 * PSTRIDE + base]) = B;
        }
    }
    __syncthreads();

    // ---- gather: 4 independent px chains per thread ----
    float res[12];
    #pragma unroll
    for (int s = 0; s < 4; ++s) {
        const float dy = (s == 0) ? fl0.x : (s == 1) ? fl0.z : (s == 2) ? fl1.x : fl1.z;
        const float dx = (s == 0) ? fl0.y : (s == 1) ? fl0.w : (s == 2) ? fl1.y : fl1.w;
        const int xs = xq + s;

        const float qy = (float)y  - dy;
        const float qx = (float)xs - dx;
        const float y0f = fminf(fmaxf(floorf(qy), 0.0f), (float)(HH - 2));
        const float x0f = fminf(fmaxf(floorf(qx), 0.0f), (float)(WW - 2));
        const float ay = fminf(fmaxf(qy - y0f, 0.0f), 1.0f);
        const float ax = fminf(fmaxf(qx - x0f, 0.0f), 1.0f);
        const int y0 = (int)y0f;
        const int x0 = (int)x0f;

        float tl0, tl1, tl2, tr0, tr1, tr2, bl0, bl1, bl2, br0, br1, br2;
        if (y0 >= r0 && y0 < r0 + SR - 1 && x0 >= c0 && x0 < c0 + SC - 1) {
            const int o = (y0 - r0) * SC + (x0 - c0);
            // R plane: pairs (o,o+1) and (o+SC,o+SC+1) -> ds_read2_b32
            tl0 = lds[o];                tr0 = lds[o + 1];
            bl0 = lds[o + SC];           br0 = lds[o + SC + 1];
            tl1 = lds[PSTRIDE + o];      tr1 = lds[PSTRIDE + o + 1];
            bl1 = lds[PSTRIDE + o + SC]; br1 = lds[PSTRIDE + o + SC + 1];
            tl2 = lds[2*PSTRIDE + o];      tr2 = lds[2*PSTRIDE + o + 1];
            bl2 = lds[2*PSTRIDE + o + SC]; br2 = lds[2*PSTRIDE + o + SC + 1];
        } else {
            // |flow| > HALO outlier (P ~ 1e-15): exact fallback from global
            const float* rowt = img + ((size_t)((b * HH + y0) * WW + x0)) * 3;
            const float* rowb = rowt + WW * 3;
            const float3 tl = *reinterpret_cast<const float3*>(rowt);
            const float3 tr = *reinterpret_cast<const float3*>(rowt + 3);
            const float3 bl = *reinterpret_cast<const float3*>(rowb);
            const float3 br = *reinterpret_cast<const float3*>(rowb + 3);
            tl0 = tl.x; tl1 = tl.y; tl2 = tl.z;
            tr0 = tr.x; tr1 = tr.y; tr2 = tr.z;
            bl0 = bl.x; bl1 = bl.y; bl2 = bl.z;
            br0 = br.x; br1 = br.y; br2 = br.z;
        }

        const float t0 = fmaf(ax, tr0 - tl0, tl0);
        const float t1 = fmaf(ax, tr1 - tl1, tl1);
        const float t2 = fmaf(ax, tr2 - tl2, tl2);
        const float q0 = fmaf(ax, br0 - bl0, bl0);
        const float q1 = fmaf(ax, br1 - bl1, bl1);
        const float q2 = fmaf(ax, br2 - bl2, bl2);
        res[3 * s + 0] = fmaf(ay, q0 - t0, t0);
        res[3 * s + 1] = fmaf(ay, q1 - t1, t1);
        res[3 * s + 2] = fmaf(ay, q2 - t2, t2);
    }

    // ---- store 4 px = 48B contiguous, 16B-aligned ----
    float* o = out + 3 * (((size_t)which) * NPIX + pixbase);
    const vf4 s0 = {res[0], res[1], res[2],  res[3]};
    const vf4 s1 = {res[4], res[5], res[6],  res[7]};
    const vf4 s2 = {res[8], res[9], res[10], res[11]};
    *reinterpret_cast<vf4*>(o)     = s0;
    *reinterpret_cast<vf4*>(o + 4) = s1;
    *reinterpret_cast<vf4*>(o + 8) = s2;
}

extern "C" void kernel_launch(void* const* d_in, const int* in_sizes, int n_in,
                              void* d_out, int out_size, void* d_ws, size_t ws_size,
                              hipStream_t stream) {
    const float* frame0 = (const float*)d_in[0];
    const float* frame1 = (const float*)d_in[1];
    const float* f01    = (const float*)d_in[2];
    const float* f10    = (const float*)d_in[3];
    float* out = (float*)d_out;

    // 2 outputs * 16 batches * 32 rowtiles * 8 coltiles = 8192 blocks
    warp2_kernel<<<8192, 256, 0, stream>>>(frame0, frame1, f01, f10, out);
}

// Round 9
// 57.447 us; speedup vs baseline: 1.3777x; 1.1460x over previous
//
#include <hip/hip_runtime.h>

#define BB 16
#define HH 512
#define WW 512
#define TH 16
#define TW 64
#define HALO 8
#define SR 33                 // staged rows = TH + 2*HALO + 1
#define SC 80                 // staged cols (px) = TW + 2*HALO
#define ROWQ (SC / 4)         // 20 quad-px staging units per row
#define NUNIT (SR * ROWQ)     // 660
#define NPIX (BB * HH * WW)

typedef float vf4 __attribute__((ext_vector_type(4)));
typedef unsigned int u32;
typedef u32 vu4 __attribute__((ext_vector_type(4)));
typedef u32 vu2 __attribute__((ext_vector_type(2)));

__device__ __forceinline__ u32 cvt_pk_bf16(float lo, float hi) {
    u32 r;
    asm("v_cvt_pk_bf16_f32 %0, %1, %2" : "=v"(r) : "v"(lo), "v"(hi));
    return r;   // low16 = bf16(lo), high16 = bf16(hi), RNE
}
__device__ __forceinline__ float bf_lo(u32 w) { return __uint_as_float(w << 16); }
__device__ __forceinline__ float bf_hi(u32 w) { return __uint_as_float(w & 0xffff0000u); }

__global__ __launch_bounds__(256, 7) void warp2_kernel(
    const float* __restrict__ frame0,
    const float* __restrict__ frame1,
    const float* __restrict__ f01,
    const float* __restrict__ f10,
    float* __restrict__ out)
{
    __shared__ vu2 plds[SR * SC];        // 8 B per pixel -> 21,120 B -> 7 blocks/CU

    // ---- tile decode, bijective XCD-chunked swizzle (8192 = 8 * 1024) ----
    const int bid = blockIdx.x;
    const int gt  = (bid & 7) * 1024 + (bid >> 3);
    const int which = gt >> 12;          // 4096 tiles per output
    const int b     = (gt >> 8) & 15;
    const int tt    = gt & 255;
    const int ty    = (tt >> 3) * TH;    // 32 rowtiles
    const int tx    = (tt & 7) * TW;     // 8 coltiles, fastest -> L2 reuse

    const float* __restrict__ img  = which ? frame1 : frame0;
    const float* __restrict__ flow = which ? f01    : f10;

    const int r0 = min(max(ty - HALO, 0), HH - SR);
    const int c0 = min(max(tx - HALO, 0), WW - SC);

    const int tid = threadIdx.x;

    // ---- flow prefetch (latency hides under staging) ----
    const int r  = tid >> 4;             // 0..15 row in tile
    const int q  = tid & 15;             // 0..15 quad in row
    const int y  = ty + r;
    const int xq = tx + (q << 2);
    const size_t pixbase = (size_t)(b * HH + y) * WW + xq;
    const vf4 fl0 = __builtin_nontemporal_load(reinterpret_cast<const vf4*>(flow + 2 * pixbase));
    const vf4 fl1 = __builtin_nontemporal_load(reinterpret_cast<const vf4*>(flow + 2 * pixbase + 4));

    // ---- stage 660 quad-px units as packed bf16 (8 B/px) ----
    #pragma unroll
    for (int it = 0; it < 3; ++it) {
        const int s = tid + (it << 8);
        if (it < 2 || s < NUNIT) {
            const int row = s / ROWQ;                 // const divisor -> magic mul
            const int u   = s - row * ROWQ;
            const float* g = img + ((size_t)((b * HH + r0 + row) * WW + c0 + (u << 2))) * 3;
            const vf4 a0 = *reinterpret_cast<const vf4*>(g);      // R0 G0 B0 R1
            const vf4 a1 = *reinterpret_cast<const vf4*>(g + 4);  // G1 B1 R2 G2
            const vf4 a2 = *reinterpret_cast<const vf4*>(g + 8);  // B2 R3 G3 B3
            const vu4 w0 = { cvt_pk_bf16(a0.x, a0.y), cvt_pk_bf16(a0.z, 0.0f),
                             cvt_pk_bf16(a0.w, a1.x), cvt_pk_bf16(a1.y, 0.0f) };
            const vu4 w1 = { cvt_pk_bf16(a1.z, a1.w), cvt_pk_bf16(a2.x, 0.0f),
                             cvt_pk_bf16(a2.y, a2.z), cvt_pk_bf16(a2.w, 0.0f) };
            const int base = row * SC + (u << 2);     // even -> 16B-aligned
            *reinterpret_cast<vu4*>(&plds[base])     = w0;
            *reinterpret_cast<vu4*>(&plds[base + 2]) = w1;
        }
    }
    __syncthreads();

    // ---- gather: 4 independent px chains per thread ----
    float res[12];
    #pragma unroll
    for (int s = 0; s < 4; ++s) {
        const float dy = (s == 0) ? fl0.x : (s == 1) ? fl0.z : (s == 2) ? fl1.x : fl1.z;
        const float dx = (s == 0) ? fl0.y : (s == 1) ? fl0.w : (s == 2) ? fl1.y : fl1.w;
        const int xs = xq + s;

        const float qy = (float)y  - dy;
        const float qx = (float)xs - dx;
        const float y0f = fminf(fmaxf(floorf(qy), 0.0f), (float)(HH - 2));
        const float x0f = fminf(fmaxf(floorf(qx), 0.0f), (float)(WW - 2));
        const float ay = fminf(fmaxf(qy - y0f, 0.0f), 1.0f);
        const float ax = fminf(fmaxf(qx - x0f, 0.0f), 1.0f);
        const int y0 = (int)y0f;
        const int x0 = (int)x0f;

        float tl0, tl1, tl2, tr0, tr1, tr2, bl0, bl1, bl2, br0, br1, br2;
        if (y0 >= r0 && y0 < r0 + SR - 1 && x0 >= c0 && x0 < c0 + SC - 1) {
            const int o = (y0 - r0) * SC + (x0 - c0);
            // tl/tr and bl/br are adjacent 8B slots -> ds_read2_b64 pairs
            const vu2 tl = plds[o];      const vu2 tr = plds[o + 1];
            const vu2 bl = plds[o + SC]; const vu2 br = plds[o + SC + 1];
            tl0 = bf_lo(tl.x); tl1 = bf_hi(tl.x); tl2 = bf_lo(tl.y);
            tr0 = bf_lo(tr.x); tr1 = bf_hi(tr.x); tr2 = bf_lo(tr.y);
            bl0 = bf_lo(bl.x); bl1 = bf_hi(bl.x); bl2 = bf_lo(bl.y);
            br0 = bf_lo(br.x); br1 = bf_hi(br.x); br2 = bf_lo(br.y);
        } else {
            // |flow| > HALO outlier (P ~ 1e-12): exact fp32 fallback from global
            const float* rowt = img + ((size_t)((b * HH + y0) * WW + x0)) * 3;
            const float* rowb = rowt + WW * 3;
            const float3 tl = *reinterpret_cast<const float3*>(rowt);
            const float3 tr = *reinterpret_cast<const float3*>(rowt + 3);
            const float3 bl = *reinterpret_cast<const float3*>(rowb);
            const float3 br = *reinterpret_cast<const float3*>(rowb + 3);
            tl0 = tl.x; tl1 = tl.y; tl2 = tl.z;
            tr0 = tr.x; tr1 = tr.y; tr2 = tr.z;
            bl0 = bl.x; bl1 = bl.y; bl2 = bl.z;
            br0 = br.x; br1 = br.y; br2 = br.z;
        }

        const float t0 = fmaf(ax, tr0 - tl0, tl0);
        const float t1 = fmaf(ax, tr1 - tl1, tl1);
        const float t2 = fmaf(ax, tr2 - tl2, tl2);
        const float q0 = fmaf(ax, br0 - bl0, bl0);
        const float q1 = fmaf(ax, br1 - bl1, bl1);
        const float q2 = fmaf(ax, br2 - bl2, bl2);
        res[3 * s + 0] = fmaf(ay, q0 - t0, t0);
        res[3 * s + 1] = fmaf(ay, q1 - t1, t1);
        res[3 * s + 2] = fmaf(ay, q2 - t2, t2);
    }

    // ---- store 4 px = 48B contiguous, 16B-aligned ----
    float* o = out + 3 * (((size_t)which) * NPIX + pixbase);
    const vf4 s0 = {res[0], res[1], res[2],  res[3]};
    const vf4 s1 = {res[4], res[5], res[6],  res[7]};
    const vf4 s2 = {res[8], res[9], res[10], res[11]};
    *reinterpret_cast<vf4*>(o)     = s0;
    *reinterpret_cast<vf4*>(o + 4) = s1;
    *reinterpret_cast<vf4*>(o + 8) = s2;
}

extern "C" void kernel_launch(void* const* d_in, const int* in_sizes, int n_in,
                              void* d_out, int out_size, void* d_ws, size_t ws_size,
                              hipStream_t stream) {
    const float* frame0 = (const float*)d_in[0];
    const float* frame1 = (const float*)d_in[1];
    const float* f01    = (const float*)d_in[2];
    const float* f10    = (const float*)d_in[3];
    float* out = (float*)d_out;

    // 2 outputs * 16 batches * 32 rowtiles * 8 coltiles = 8192 blocks
    warp2_kernel<<<8192, 256, 0, stream>>>(frame0, frame1, f01, f10, out);
}